// Round 4
// baseline (497.786 us; speedup 1.0000x reference)
//
#include <hip/hip_runtime.h>

// Problem constants
#define BB 2
#define SS 2048
#define DD 1024
#define HH 16
#define HD 64
#define NREL 129
#define LOG2E 1.4426950408889634f

typedef short s8v __attribute__((ext_vector_type(8)));
typedef float f4 __attribute__((ext_vector_type(4)));

#define MFMA_BF16 __builtin_amdgcn_mfma_f32_16x16x32_bf16

__device__ __forceinline__ unsigned short f2bf(float f) {
  union { float f; unsigned int i; } x; x.f = f;
  unsigned int r = x.i + 0x7fffu + ((x.i >> 16) & 1u);
  return (unsigned short)(r >> 16);
}

// ---------------------------------------------------------------------------
// Weight transpose+convert: W fp32 [1024 k][1024 n] -> WT bf16 [1024 n][1024 k]
// grid (16, 16, 3), block 256
__global__ __launch_bounds__(256) void cvt_w(
    const float* __restrict__ Wq, const float* __restrict__ Wk,
    const float* __restrict__ Wv, unsigned short* __restrict__ WTbase) {
  __shared__ unsigned short tile[64][72];
  const int z = blockIdx.z;
  const float* in = (z == 0) ? Wq : (z == 1) ? Wk : Wv;
  unsigned short* out = WTbase + (long)z * DD * DD;
  const int c0 = blockIdx.x * 64, r0 = blockIdx.y * 64;
  const int t = threadIdx.x;
  const int r = t >> 2;
  #pragma unroll
  for (int j = 0; j < 4; ++j) {
    int cc = (t & 3) * 16 + j * 4;
    f4 v = *(const f4*)(in + (long)(r0 + r) * DD + c0 + cc);
    #pragma unroll
    for (int e = 0; e < 4; ++e) tile[r][cc + e] = f2bf(v[e]);
  }
  __syncthreads();
  const int c = t >> 2;
  #pragma unroll
  for (int h = 0; h < 2; ++h) {
    int r8 = (t & 3) + 4 * h;
    unsigned short vals[8];
    #pragma unroll
    for (int j = 0; j < 8; ++j) vals[j] = tile[r8 * 8 + j][c];
    *(s8v*)(out + (long)(c0 + c) * DD + r0 + r8 * 8) = *(s8v*)vals;
  }
}

// ---------------------------------------------------------------------------
// bf16 tile transpose (for V): out[b][c][r] = in[b][r][c]
// grid (C/64, R/64, batches), block 256
__global__ __launch_bounds__(256) void transpose_bf16(
    const unsigned short* __restrict__ in, unsigned short* __restrict__ out,
    int R, int C, long inBatch, long outBatch) {
  __shared__ unsigned short tile[64][72];
  const int c0 = blockIdx.x * 64, r0 = blockIdx.y * 64;
  const unsigned short* ip = in + (long)blockIdx.z * inBatch;
  unsigned short* op = out + (long)blockIdx.z * outBatch;
  const int t = threadIdx.x;
  const int r = t >> 2;
  #pragma unroll
  for (int h = 0; h < 2; ++h) {
    int c8 = (t & 3) + 4 * h;
    *(s8v*)&tile[r][c8 * 8] = *(const s8v*)(ip + (long)(r0 + r) * C + c0 + c8 * 8);
  }
  __syncthreads();
  const int c = t >> 2;
  #pragma unroll
  for (int h = 0; h < 2; ++h) {
    int r8 = (t & 3) + 4 * h;
    unsigned short vals[8];
    #pragma unroll
    for (int j = 0; j < 8; ++j) vals[j] = tile[r8 * 8 + j][c];
    *(s8v*)(op + (long)(c0 + c) * R + r0 + r8 * 8) = *(s8v*)vals;
  }
}

// ---------------------------------------------------------------------------
// Fused QKV projection GEMM: C = X @ W + bias, head-split [bh][s][d] bf16.
// X fp32 [4096][1024] converted in-register; WT bf16 [n][k]. grid (8, 64, 3).
__global__ __launch_bounds__(256) void proj_gemm(
    const float* __restrict__ Xq, const float* __restrict__ Xk,
    const float* __restrict__ Xv, const unsigned short* __restrict__ WTbase,
    const float* __restrict__ bq, const float* __restrict__ bk,
    const float* __restrict__ bv,
    unsigned short* __restrict__ qbuf, unsigned short* __restrict__ kbuf,
    unsigned short* __restrict__ vbuf) {
  __shared__ unsigned short wt[128][72];
  const int z = blockIdx.z;
  const float* X = (z == 0) ? Xq : (z == 1) ? Xk : Xv;
  const unsigned short* WT = WTbase + (long)z * DD * DD;
  const float* bias = (z == 0) ? bq : (z == 1) ? bk : bv;
  unsigned short* out = (z == 0) ? qbuf : (z == 1) ? kbuf : vbuf;

  const int n0 = blockIdx.x * 128, m0 = blockIdx.y * 64;
  const int t = threadIdx.x, w = t >> 6, l = t & 63;
  const int lm = l & 15, qd = l >> 4;
  const long row = m0 + w * 16 + lm;

  f4 acc[8];
  #pragma unroll
  for (int i = 0; i < 8; ++i) acc[i] = (f4)0.0f;

  for (int k0 = 0; k0 < DD; k0 += 64) {
    __syncthreads();
    #pragma unroll
    for (int i = 0; i < 4; ++i) {
      int idx = t + i * 256;
      int n = idx >> 3, kc = idx & 7;
      *(s8v*)&wt[n][kc * 8] = *(const s8v*)(WT + (long)(n0 + n) * DD + k0 + kc * 8);
    }
    __syncthreads();
    const float* xr = X + row * DD + k0;
    f4 v0 = *(const f4*)(xr + qd * 8), v1 = *(const f4*)(xr + qd * 8 + 4);
    f4 v2 = *(const f4*)(xr + 32 + qd * 8), v3 = *(const f4*)(xr + 32 + qd * 8 + 4);
    unsigned short u[16];
    #pragma unroll
    for (int e = 0; e < 4; ++e) {
      u[e] = f2bf(v0[e]); u[4 + e] = f2bf(v1[e]);
      u[8 + e] = f2bf(v2[e]); u[12 + e] = f2bf(v3[e]);
    }
    s8v a0 = *(s8v*)u, a1 = *(s8v*)(u + 8);
    #pragma unroll
    for (int cb = 0; cb < 8; ++cb) {
      s8v b0 = *(const s8v*)&wt[cb * 16 + lm][qd * 8];
      s8v b1 = *(const s8v*)&wt[cb * 16 + lm][32 + qd * 8];
      acc[cb] = MFMA_BF16(a0, b0, acc[cb], 0, 0, 0);
      acc[cb] = MFMA_BF16(a1, b1, acc[cb], 0, 0, 0);
    }
  }
  #pragma unroll
  for (int cb = 0; cb < 8; ++cb) {
    int n = n0 + cb * 16 + lm;
    float bvv = bias[n];
    int h = n >> 6, d = n & 63;
    #pragma unroll
    for (int r = 0; r < 4; ++r) {
      int m = m0 + w * 16 + qd * 4 + r;
      int b = m >> 11, s = m & (SS - 1);
      out[((long)(b * HH + h) * SS + s) * HD + d] = f2bf(acc[cb][r] + bvv);
    }
  }
}

// ---------------------------------------------------------------------------
// Flash attention with fused rel-pos key bias; fp32 output.
// grid (32 q-blocks, 32 bh), block 256 (4 waves x 16 q rows each)
__global__ __launch_bounds__(256) void attn(
    const unsigned short* __restrict__ qb, const unsigned short* __restrict__ kb,
    const unsigned short* __restrict__ vt, const float* __restrict__ tableF,
    const float* __restrict__ maskF, float* __restrict__ out) {
  __shared__ float qr[64][145];              // wave w owns rows w*16..w*16+15
  __shared__ unsigned short pbuf[4][16][40]; // per-wave P transpose buffer

  const int bh = blockIdx.y, b = bh >> 4, h = bh & 15;
  const int q0 = blockIdx.x * 64;
  const int t = threadIdx.x, w = t >> 6, l = t & 63;
  const int lm = l & 15, qd = l >> 4;

  // Q fragments (rows q0 + w*16 + lm) held for the whole kernel
  const unsigned short* qrow = qb + ((long)bh * SS + q0 + w * 16 + lm) * HD;
  const s8v a0 = *(const s8v*)(qrow + qd * 8);
  const s8v a1 = *(const s8v*)(qrow + 32 + qd * 8);

  // Fused qrel: qr[qi_loc][dist] = q_row . table[dist] (table fp32, inline cvt)
  #pragma unroll
  for (int cb = 0; cb < 9; ++cb) {
    int dist = cb * 16 + lm;
    if (dist > NREL - 1) dist = NREL - 1;   // cols >=129 unused
    const float* trow = tableF + dist * HD;
    f4 t0 = *(const f4*)(trow + qd * 8);
    f4 t1 = *(const f4*)(trow + qd * 8 + 4);
    f4 t2 = *(const f4*)(trow + 32 + qd * 8);
    f4 t3 = *(const f4*)(trow + 32 + qd * 8 + 4);
    unsigned short tb[16];
    #pragma unroll
    for (int e = 0; e < 4; ++e) {
      tb[e] = f2bf(t0[e]); tb[4 + e] = f2bf(t1[e]);
      tb[8 + e] = f2bf(t2[e]); tb[12 + e] = f2bf(t3[e]);
    }
    s8v b0 = *(s8v*)tb, b1 = *(s8v*)(tb + 8);
    f4 c = MFMA_BF16(a0, b0, (f4)0.0f, 0, 0, 0);
    c = MFMA_BF16(a1, b1, c, 0, 0, 0);
    #pragma unroll
    for (int r = 0; r < 4; ++r)
      qr[w * 16 + qd * 4 + r][cb * 16 + lm] = c[r];
  }
  asm volatile("s_waitcnt lgkmcnt(0)" ::: "memory");

  const float SCL = LOG2E / 8.0f;  // 1/sqrt(64) * log2(e)
  float m_[4], l_[4];
  f4 c4[4];
  #pragma unroll
  for (int r = 0; r < 4; ++r) { m_[r] = -1e30f; l_[r] = 0.0f; }
  #pragma unroll
  for (int i = 0; i < 4; ++i) c4[i] = (f4)0.0f;

  for (int k0 = 0; k0 < SS; k0 += 32) {
    float z[2][4];
    #pragma unroll
    for (int cb = 0; cb < 2; ++cb) {
      const unsigned short* krow = kb + ((long)bh * SS + k0 + cb * 16 + lm) * HD;
      s8v b0 = *(const s8v*)(krow + qd * 8);
      s8v b1 = *(const s8v*)(krow + 32 + qd * 8);
      f4 sc = MFMA_BF16(a0, b0, (f4)0.0f, 0, 0, 0);
      sc = MFMA_BF16(a1, b1, sc, 0, 0, 0);
      int ki = k0 + cb * 16 + lm;
      float mval = maskF[b * SS + ki] * LOG2E;
      #pragma unroll
      for (int r = 0; r < 4; ++r) {
        int qi_loc = w * 16 + qd * 4 + r;
        int dist = ki - (q0 + qi_loc);
        dist = (dist < -64) ? -64 : (dist > 64 ? 64 : dist);
        float bias = qr[qi_loc][dist + 64];
        z[cb][r] = (sc[r] + bias) * SCL + mval;
      }
    }
    #pragma unroll
    for (int r = 0; r < 4; ++r) {
      float tm = fmaxf(z[0][r], z[1][r]);
      tm = fmaxf(tm, __shfl_xor(tm, 1));
      tm = fmaxf(tm, __shfl_xor(tm, 2));
      tm = fmaxf(tm, __shfl_xor(tm, 4));
      tm = fmaxf(tm, __shfl_xor(tm, 8));
      float mn = fmaxf(m_[r], tm);
      float alpha = exp2f(m_[r] - mn);
      m_[r] = mn;
      float p0 = exp2f(z[0][r] - mn), p1 = exp2f(z[1][r] - mn);
      float ts = p0 + p1;
      ts += __shfl_xor(ts, 1);
      ts += __shfl_xor(ts, 2);
      ts += __shfl_xor(ts, 4);
      ts += __shfl_xor(ts, 8);
      l_[r] = l_[r] * alpha + ts;
      #pragma unroll
      for (int db = 0; db < 4; ++db) c4[db][r] *= alpha;
      pbuf[w][qd * 4 + r][lm] = f2bf(p0);
      pbuf[w][qd * 4 + r][16 + lm] = f2bf(p1);
    }
    asm volatile("s_waitcnt lgkmcnt(0)" ::: "memory");
    s8v pa = *(const s8v*)&pbuf[w][lm][qd * 8];
    #pragma unroll
    for (int db = 0; db < 4; ++db) {
      const unsigned short* vrow = vt + ((long)bh * HD + db * 16 + lm) * SS + k0 + qd * 8;
      s8v vb = *(const s8v*)vrow;
      c4[db] = MFMA_BF16(pa, vb, c4[db], 0, 0, 0);
    }
  }

  // epilogue: fp32 output [B][S][D]
  #pragma unroll
  for (int r = 0; r < 4; ++r) {
    float inv = 1.0f / l_[r];
    int s = q0 + w * 16 + qd * 4 + r;
    #pragma unroll
    for (int db = 0; db < 4; ++db) {
      int d = h * HD + db * 16 + lm;
      out[((long)b * SS + s) * DD + d] = c4[db][r] * inv;
    }
  }
}

// ---------------------------------------------------------------------------
extern "C" void kernel_launch(void* const* d_in, const int* in_sizes, int n_in,
                              void* d_out, int out_size, void* d_ws, size_t ws_size,
                              hipStream_t stream) {
  const float* query = (const float*)d_in[0];
  const float* key   = (const float*)d_in[1];
  const float* value = (const float*)d_in[2];
  const float* mask  = (const float*)d_in[3];
  const float* Wq    = (const float*)d_in[4];
  const float* bq    = (const float*)d_in[5];
  const float* Wk    = (const float*)d_in[6];
  const float* bk    = (const float*)d_in[7];
  const float* Wv    = (const float*)d_in[8];
  const float* bv    = (const float*)d_in[9];
  const float* table = (const float*)d_in[10];

  char* ws = (char*)d_ws;
  // workspace layout (bytes), span 40 MB
  unsigned short* WT   = (unsigned short*)(ws);               // 6,291,456
  unsigned short* qbuf = (unsigned short*)(ws + (8l << 20));  // 8,388,608
  unsigned short* kbuf = (unsigned short*)(ws + (16l << 20)); // 8,388,608
  unsigned short* vbuf = (unsigned short*)(ws + (24l << 20)); // 8,388,608
  unsigned short* vT   = (unsigned short*)(ws + (32l << 20)); // 8,388,608

  // 1) transpose+convert weights: WT[z][n][k] = W[z][k][n]
  cvt_w<<<dim3(16, 16, 3), 256, 0, stream>>>(Wq, Wk, Wv, WT);

  // 2) fused QKV projections -> head-split bf16 [bh][s][d]
  proj_gemm<<<dim3(8, 64, 3), 256, 0, stream>>>(query, key, value, WT,
                                                bq, bk, bv, qbuf, kbuf, vbuf);

  // 3) transpose V per (b,h): vT[bh][d][s]
  transpose_bf16<<<dim3(1, 32, 32), 256, 0, stream>>>(vbuf, vT, 2048, 64,
                                                      (long)2048 * 64, (long)2048 * 64);

  // 4) flash attention with fused rel bias, fp32 output
  attn<<<dim3(32, 32, 1), 256, 0, stream>>>(qbuf, kbuf, vT, table, mask,
                                            (float*)d_out);
}

// Round 5
// 436.369 us; speedup vs baseline: 1.1407x; 1.1407x over previous
//
#include <hip/hip_runtime.h>

// Problem constants
#define BB 2
#define SS 2048
#define DD 1024
#define HH 16
#define HD 64
#define NREL 129
#define LOG2E 1.4426950408889634f

typedef short s8v __attribute__((ext_vector_type(8)));
typedef float f4 __attribute__((ext_vector_type(4)));

#define MFMA_BF16 __builtin_amdgcn_mfma_f32_16x16x32_bf16

__device__ __forceinline__ float bf2f(unsigned short u) {
  union { unsigned int i; float f; } x; x.i = ((unsigned int)u) << 16; return x.f;
}
__device__ __forceinline__ unsigned short f2bf(float f) {
  union { float f; unsigned int i; } x; x.f = f;
  unsigned int r = x.i + 0x7fffu + ((x.i >> 16) & 1u);
  return (unsigned short)(r >> 16);
}

// ---------------------------------------------------------------------------
// Weight transpose+convert: W fp32 [1024 k][1024 n] -> WT bf16 [1024 n][1024 k]
// grid (16, 16, 3), block 256
__global__ __launch_bounds__(256) void cvt_w(
    const float* __restrict__ Wq, const float* __restrict__ Wk,
    const float* __restrict__ Wv, unsigned short* __restrict__ WTbase) {
  __shared__ unsigned short tile[64][72];
  const int z = blockIdx.z;
  const float* in = (z == 0) ? Wq : (z == 1) ? Wk : Wv;
  unsigned short* out = WTbase + (long)z * DD * DD;
  const int c0 = blockIdx.x * 64, r0 = blockIdx.y * 64;
  const int t = threadIdx.x;
  const int r = t >> 2;
  #pragma unroll
  for (int j = 0; j < 4; ++j) {
    int cc = (t & 3) * 16 + j * 4;
    f4 v = *(const f4*)(in + (long)(r0 + r) * DD + c0 + cc);
    #pragma unroll
    for (int e = 0; e < 4; ++e) tile[r][cc + e] = f2bf(v[e]);
  }
  __syncthreads();
  const int c = t >> 2;
  #pragma unroll
  for (int h = 0; h < 2; ++h) {
    int r8 = (t & 3) + 4 * h;
    unsigned short vals[8];
    #pragma unroll
    for (int j = 0; j < 8; ++j) vals[j] = tile[r8 * 8 + j][c];
    *(s8v*)(out + (long)(c0 + c) * DD + r0 + r8 * 8) = *(s8v*)vals;
  }
}

// ---------------------------------------------------------------------------
// bf16 tile transpose (for V): out[b][c][r] = in[b][r][c]
// grid (C/64, R/64, batches), block 256
__global__ __launch_bounds__(256) void transpose_bf16(
    const unsigned short* __restrict__ in, unsigned short* __restrict__ out,
    int R, int C, long inBatch, long outBatch) {
  __shared__ unsigned short tile[64][72];
  const int c0 = blockIdx.x * 64, r0 = blockIdx.y * 64;
  const unsigned short* ip = in + (long)blockIdx.z * inBatch;
  unsigned short* op = out + (long)blockIdx.z * outBatch;
  const int t = threadIdx.x;
  const int r = t >> 2;
  #pragma unroll
  for (int h = 0; h < 2; ++h) {
    int c8 = (t & 3) + 4 * h;
    *(s8v*)&tile[r][c8 * 8] = *(const s8v*)(ip + (long)(r0 + r) * C + c0 + c8 * 8);
  }
  __syncthreads();
  const int c = t >> 2;
  #pragma unroll
  for (int h = 0; h < 2; ++h) {
    int r8 = (t & 3) + 4 * h;
    unsigned short vals[8];
    #pragma unroll
    for (int j = 0; j < 8; ++j) vals[j] = tile[r8 * 8 + j][c];
    *(s8v*)(op + (long)(c0 + c) * R + r0 + r8 * 8) = *(s8v*)vals;
  }
}

// ---------------------------------------------------------------------------
// Fused QKV projection GEMM: C = X @ W + bias, head-split [bh][s][d] bf16.
// n-tile 256 (halves fp32-X re-reads vs 128). grid (4, 64, 3), block 256.
__global__ __launch_bounds__(256) void proj_gemm(
    const float* __restrict__ Xq, const float* __restrict__ Xk,
    const float* __restrict__ Xv, const unsigned short* __restrict__ WTbase,
    const float* __restrict__ bq, const float* __restrict__ bk,
    const float* __restrict__ bv,
    unsigned short* __restrict__ qbuf, unsigned short* __restrict__ kbuf,
    unsigned short* __restrict__ vbuf) {
  __shared__ unsigned short wt[256][72];
  const int z = blockIdx.z;
  const float* X = (z == 0) ? Xq : (z == 1) ? Xk : Xv;
  const unsigned short* WT = WTbase + (long)z * DD * DD;
  const float* bias = (z == 0) ? bq : (z == 1) ? bk : bv;
  unsigned short* out = (z == 0) ? qbuf : (z == 1) ? kbuf : vbuf;

  const int n0 = blockIdx.x * 256, m0 = blockIdx.y * 64;
  const int t = threadIdx.x, w = t >> 6, l = t & 63;
  const int lm = l & 15, qd = l >> 4;
  const long row = m0 + w * 16 + lm;

  f4 acc[16];
  #pragma unroll
  for (int i = 0; i < 16; ++i) acc[i] = (f4)0.0f;

  for (int k0 = 0; k0 < DD; k0 += 64) {
    __syncthreads();
    #pragma unroll
    for (int i = 0; i < 8; ++i) {
      int idx = t + i * 256;            // 0..2047
      int n = idx >> 3, kc = idx & 7;   // n 0..255
      *(s8v*)&wt[n][kc * 8] = *(const s8v*)(WT + (long)(n0 + n) * DD + k0 + kc * 8);
    }
    __syncthreads();
    const float* xr = X + row * DD + k0;
    f4 v0 = *(const f4*)(xr + qd * 8), v1 = *(const f4*)(xr + qd * 8 + 4);
    f4 v2 = *(const f4*)(xr + 32 + qd * 8), v3 = *(const f4*)(xr + 32 + qd * 8 + 4);
    unsigned short u[16];
    #pragma unroll
    for (int e = 0; e < 4; ++e) {
      u[e] = f2bf(v0[e]); u[4 + e] = f2bf(v1[e]);
      u[8 + e] = f2bf(v2[e]); u[12 + e] = f2bf(v3[e]);
    }
    s8v a0 = *(s8v*)u, a1 = *(s8v*)(u + 8);
    #pragma unroll
    for (int cb = 0; cb < 16; ++cb) {
      s8v b0 = *(const s8v*)&wt[cb * 16 + lm][qd * 8];
      s8v b1 = *(const s8v*)&wt[cb * 16 + lm][32 + qd * 8];
      acc[cb] = MFMA_BF16(a0, b0, acc[cb], 0, 0, 0);
      acc[cb] = MFMA_BF16(a1, b1, acc[cb], 0, 0, 0);
    }
  }
  #pragma unroll
  for (int cb = 0; cb < 16; ++cb) {
    int n = n0 + cb * 16 + lm;
    float bvv = bias[n];
    int h = n >> 6, d = n & 63;
    #pragma unroll
    for (int r = 0; r < 4; ++r) {
      int m = m0 + w * 16 + qd * 4 + r;
      int b = m >> 11, s = m & (SS - 1);
      out[((long)(b * HH + h) * SS + s) * HD + d] = f2bf(acc[cb][r] + bvv);
    }
  }
}

// ---------------------------------------------------------------------------
// Flash attention, S-transposed formulation:
//   S^T = MFMA(A=K, B=Q)  -> C[key][q], q = lane&15  (softmax state per-lane!)
//   O^T = MFMA(A=V^T, B=P^T) -> C[d][q]
// Per 32-key iter: 4 shuffles total (vs 32 in row-major form).
// grid (32 q-blocks, 32 bh), block 256 (4 waves x 16 q's each)
__global__ __launch_bounds__(256) void attn(
    const unsigned short* __restrict__ qb, const unsigned short* __restrict__ kb,
    const unsigned short* __restrict__ vt, const float* __restrict__ tableF,
    const float* __restrict__ maskF, float* __restrict__ out) {
  __shared__ unsigned short pbuf[4][16][40]; // per-wave P (q-major), 16B-aligned rows
  __shared__ float mk[SS];                   // mask row * LOG2E
  __shared__ unsigned short qr2[NREL][66];   // [dist][q_local], stride 66: 2-way banks

  const int bh = blockIdx.y, b = bh >> 4, h = bh & 15;
  const int q0 = blockIdx.x * 64;
  const int t = threadIdx.x, w = t >> 6, l = t & 63;
  const int lm = l & 15, qd = l >> 4;

  // stage mask (pre-scaled by LOG2E)
  {
    const float* mrow = maskF + b * SS;
    f4 m0v = *(const f4*)(mrow + t * 8);
    f4 m1v = *(const f4*)(mrow + t * 8 + 4);
    #pragma unroll
    for (int e = 0; e < 4; ++e) {
      mk[t * 8 + e] = m0v[e] * LOG2E;
      mk[t * 8 + 4 + e] = m1v[e] * LOG2E;
    }
  }

  // Q fragments (q = q0 + w*16 + lm) held for the whole kernel
  const unsigned short* qrow = qb + ((long)bh * SS + q0 + w * 16 + lm) * HD;
  const s8v qa0 = *(const s8v*)(qrow + qd * 8);
  const s8v qa1 = *(const s8v*)(qrow + 32 + qd * 8);

  // Fused qrel: qr2[dist][q_local] = q . table[dist]
  #pragma unroll
  for (int cb = 0; cb < 9; ++cb) {
    int dist = cb * 16 + lm;
    int dc = dist > NREL - 1 ? NREL - 1 : dist;
    const float* trow = tableF + dc * HD;
    f4 t0 = *(const f4*)(trow + qd * 8);
    f4 t1 = *(const f4*)(trow + qd * 8 + 4);
    f4 t2 = *(const f4*)(trow + 32 + qd * 8);
    f4 t3 = *(const f4*)(trow + 32 + qd * 8 + 4);
    unsigned short tb[16];
    #pragma unroll
    for (int e = 0; e < 4; ++e) {
      tb[e] = f2bf(t0[e]); tb[4 + e] = f2bf(t1[e]);
      tb[8 + e] = f2bf(t2[e]); tb[12 + e] = f2bf(t3[e]);
    }
    s8v b0 = *(s8v*)tb, b1 = *(s8v*)(tb + 8);
    f4 c = MFMA_BF16(qa0, b0, (f4)0.0f, 0, 0, 0);
    c = MFMA_BF16(qa1, b1, c, 0, 0, 0);
    if (dist <= NREL - 1) {
      #pragma unroll
      for (int r = 0; r < 4; ++r)
        qr2[dist][w * 16 + qd * 4 + r] = f2bf(c[r]);
    }
  }
  __syncthreads();

  const float SCL = LOG2E / 8.0f;  // 1/sqrt(64) * log2(e)
  float m_ = -1e30f, l_ = 0.0f;
  f4 c4[4];
  #pragma unroll
  for (int i = 0; i < 4; ++i) c4[i] = (f4)0.0f;

  const int qcol = w * 16 + lm;                  // this lane's q (block-local)
  const int dqbase = 64 + qd * 4 - (q0 + qcol);  // dist+64 base (add k0 + tile*16 + r)

  for (int k0 = 0; k0 < SS; k0 += 32) {
    // K A-fragments: tile0 keys k0+lm, tile1 keys k0+16+lm
    const unsigned short* kr0 = kb + ((long)bh * SS + k0 + lm) * HD;
    s8v ka0 = *(const s8v*)(kr0 + qd * 8);
    s8v ka1 = *(const s8v*)(kr0 + 32 + qd * 8);
    s8v kc0 = *(const s8v*)(kr0 + 16 * HD + qd * 8);
    s8v kc1 = *(const s8v*)(kr0 + 16 * HD + 32 + qd * 8);
    f4 st0 = MFMA_BF16(ka0, qa0, (f4)0.0f, 0, 0, 0);
    st0 = MFMA_BF16(ka1, qa1, st0, 0, 0, 0);
    f4 st1 = MFMA_BF16(kc0, qa0, (f4)0.0f, 0, 0, 0);
    st1 = MFMA_BF16(kc1, qa1, st1, 0, 0, 0);

    // V^T A-fragments (independent; issue early)
    s8v va[4];
    #pragma unroll
    for (int db = 0; db < 4; ++db)
      va[db] = *(const s8v*)(vt + ((long)bh * HD + db * 16 + lm) * SS + k0 + qd * 8);

    // bias + mask -> log2-domain scores; 8 keys per lane, one q
    float z[8];
    const int db0 = dqbase + k0;
    #pragma unroll
    for (int r = 0; r < 4; ++r) {
      int d0 = db0 + r;       d0 = d0 < 0 ? 0 : (d0 > 128 ? 128 : d0);
      int d1 = db0 + 16 + r;  d1 = d1 < 0 ? 0 : (d1 > 128 ? 128 : d1);
      z[r]     = (st0[r] + bf2f(qr2[d0][qcol])) * SCL + mk[k0 + qd * 4 + r];
      z[4 + r] = (st1[r] + bf2f(qr2[d1][qcol])) * SCL + mk[k0 + 16 + qd * 4 + r];
    }
    // online softmax: in-lane reduce 8, then 2 cross-quad shuffles
    float tm = fmaxf(fmaxf(fmaxf(z[0], z[1]), fmaxf(z[2], z[3])),
                     fmaxf(fmaxf(z[4], z[5]), fmaxf(z[6], z[7])));
    tm = fmaxf(tm, __shfl_xor(tm, 16));
    tm = fmaxf(tm, __shfl_xor(tm, 32));
    float mn = fmaxf(m_, tm);
    float alpha = exp2f(m_ - mn);
    m_ = mn;
    float p[8];
    #pragma unroll
    for (int i = 0; i < 8; ++i) p[i] = exp2f(z[i] - mn);
    float ts = ((p[0] + p[1]) + (p[2] + p[3])) + ((p[4] + p[5]) + (p[6] + p[7]));
    ts += __shfl_xor(ts, 16);
    ts += __shfl_xor(ts, 32);
    l_ = l_ * alpha + ts;
    #pragma unroll
    for (int db = 0; db < 4; ++db)
      #pragma unroll
      for (int r = 0; r < 4; ++r) c4[db][r] *= alpha;

    // P^T -> LDS (q-major rows) -> PV B-fragment
    #pragma unroll
    for (int r = 0; r < 4; ++r) {
      pbuf[w][lm][qd * 4 + r] = f2bf(p[r]);
      pbuf[w][lm][16 + qd * 4 + r] = f2bf(p[4 + r]);
    }
    asm volatile("s_waitcnt lgkmcnt(0)" ::: "memory");
    s8v pa = *(const s8v*)&pbuf[w][lm][qd * 8];
    #pragma unroll
    for (int db = 0; db < 4; ++db)
      c4[db] = MFMA_BF16(va[db], pa, c4[db], 0, 0, 0);
  }

  // epilogue: O^T[d][q] -> out[b][s][d], f4 stores (d contiguous per reg-quad)
  const float inv = 1.0f / l_;
  float* obase = out + ((long)b * SS + q0 + qcol) * DD + h * HD;
  #pragma unroll
  for (int db = 0; db < 4; ++db) {
    f4 o;
    #pragma unroll
    for (int r = 0; r < 4; ++r) o[r] = c4[db][r] * inv;
    *(f4*)(obase + db * 16 + qd * 4) = o;
  }
}

// ---------------------------------------------------------------------------
extern "C" void kernel_launch(void* const* d_in, const int* in_sizes, int n_in,
                              void* d_out, int out_size, void* d_ws, size_t ws_size,
                              hipStream_t stream) {
  const float* query = (const float*)d_in[0];
  const float* key   = (const float*)d_in[1];
  const float* value = (const float*)d_in[2];
  const float* mask  = (const float*)d_in[3];
  const float* Wq    = (const float*)d_in[4];
  const float* bq    = (const float*)d_in[5];
  const float* Wk    = (const float*)d_in[6];
  const float* bk    = (const float*)d_in[7];
  const float* Wv    = (const float*)d_in[8];
  const float* bv    = (const float*)d_in[9];
  const float* table = (const float*)d_in[10];

  char* ws = (char*)d_ws;
  // workspace layout (bytes), span 40 MB
  unsigned short* WT   = (unsigned short*)(ws);               // 6,291,456
  unsigned short* qbuf = (unsigned short*)(ws + (8l << 20));  // 8,388,608
  unsigned short* kbuf = (unsigned short*)(ws + (16l << 20)); // 8,388,608
  unsigned short* vbuf = (unsigned short*)(ws + (24l << 20)); // 8,388,608
  unsigned short* vT   = (unsigned short*)(ws + (32l << 20)); // 8,388,608

  // 1) transpose+convert weights: WT[z][n][k] = W[z][k][n]
  cvt_w<<<dim3(16, 16, 3), 256, 0, stream>>>(Wq, Wk, Wv, WT);

  // 2) fused QKV projections -> head-split bf16 [bh][s][d]
  proj_gemm<<<dim3(4, 64, 3), 256, 0, stream>>>(query, key, value, WT,
                                                bq, bk, bv, qbuf, kbuf, vbuf);

  // 3) transpose V per (b,h): vT[bh][d][s]
  transpose_bf16<<<dim3(1, 32, 32), 256, 0, stream>>>(vbuf, vT, 2048, 64,
                                                      (long)2048 * 64, (long)2048 * 64);

  // 4) flash attention (S-transposed), fp32 output
  attn<<<dim3(32, 32, 1), 256, 0, stream>>>(qbuf, kbuf, vT, table, mask,
                                            (float*)d_out);
}